// Round 10
// baseline (44.617 us; speedup 1.0000x reference)
//
#include <hip/hip_runtime.h>
#include <math.h>

#define NN 1024
#define K 16

typedef _Float16 f16;
typedef f16 f16x8 __attribute__((ext_vector_type(8)));
typedef float f32x4 __attribute__((ext_vector_type(4)));

// fragment region byte offsets (within f16 frag buffer; same layout in d_ws and LDS)
#define W0F_OFF 0          // 8 frags  (kt2 x nt4)
#define W1F_OFF 8192       // 32 frags (q4 x kt2 x nt4)
#define W2F_OFF 40960      // 32 frags (q4 x kt2 x nt4)
#define WLF_OFF 73728      // 2 frags  (kt2)
#define B1F_OFF 75776      // 2 frags  (kt2)
#define FRAG_BYTES 77824   // 76 frags x 1KB  (= 4864 x 16B)

#define MFMA16(a,b,c) __builtin_amdgcn_mfma_f32_16x16x32_f16((a),(b),(c),0,0,0)

// ---- DPP cross-lane helpers (VALU pipe, not DS) ----
template<int CTRL>
__device__ __forceinline__ float dppf(float v) {
    return __int_as_float(__builtin_amdgcn_update_dpp(0, __float_as_int(v), CTRL, 0xF, 0xF, true));
}
// sum over each aligned group of 16 lanes; result replicated in all 16
__device__ __forceinline__ float rowsum16(float v) {
    v += dppf<0xB1>(v);    // quad_perm [1,0,3,2]  (xor1)
    v += dppf<0x4E>(v);    // quad_perm [2,3,0,1]  (xor2)
    v += dppf<0x124>(v);   // row_ror:4
    v += dppf<0x128>(v);   // row_ror:8
    return v;
}

// -------------------- one-time weight fragmentation (tiny) --------------------
__global__ __launch_bounds__(256) void prep_kernel(const float* __restrict__ W0,
                                                   const float* __restrict__ W1,
                                                   const float* __restrict__ W2,
                                                   const float* __restrict__ Wl,
                                                   const float* __restrict__ b1,
                                                   f16* __restrict__ frag) {
    int c = blockIdx.x * 256 + threadIdx.x;   // 0..4863
    if (c >= 76 * 64) return;
    int fg   = c >> 6;
    int lane = c & 63;
    int lrow = lane & 15;
    int kgrp = lane >> 4;
    float src[8];
    if (fg < 8) {
        int kt = fg >> 2, nt = fg & 3;
        int n = nt * 16 + lrow;
#pragma unroll
        for (int i = 0; i < 8; ++i) src[i] = W0[(kt * 32 + kgrp * 8 + i) * 64 + n];
    } else if (fg < 40) {
        int t = fg - 8;
        int q = t >> 3, kt = (t >> 2) & 1, nt = t & 3;
        int f = nt * 16 + lrow;
#pragma unroll
        for (int i = 0; i < 8; ++i) src[i] = W1[f * 256 + q * 64 + kt * 32 + kgrp * 8 + i];
    } else if (fg < 72) {
        int t = fg - 40;
        int q = t >> 3, kt = (t >> 2) & 1, nt = t & 3;
        int o = nt * 16 + lrow;
#pragma unroll
        for (int i = 0; i < 8; ++i) src[i] = W2[(kt * 32 + kgrp * 8 + i) * 256 + q * 64 + o];
    } else if (fg < 74) {
        int kt = fg - 72;
#pragma unroll
        for (int i = 0; i < 8; ++i) src[i] = Wl[(kt * 32 + kgrp * 8 + i) * 16 + lrow];
    } else {
        int kt = fg - 74;
#pragma unroll
        for (int i = 0; i < 8; ++i) src[i] = b1[lrow * 64 + kt * 32 + kgrp * 8 + i];
    }
    f16x8 v;
#pragma unroll
    for (int i = 0; i < 8; ++i) v[i] = (f16)src[i];
    *(f16x8*)((unsigned char*)frag + fg * 1024 + lane * 16) = v;
}

// -------------------- fused main: topk + GEMM pipeline --------------------
// 256 blocks x 1024 threads (16 waves) = 1 block/CU. Wave = 1 node.
// Order: issue frag staging loads -> per-wave topk from D (hides load latency)
// -> LDS writes + sync -> MFMA pipeline. Neighbor indices never touch global.
__global__ __launch_bounds__(1024, 1) void node_kernel(
    const float* __restrict__ h, const float* __restrict__ D,
    const float* __restrict__ b0, const float* __restrict__ b2,
    const float* __restrict__ bl,
    const f16* __restrict__ frag,
    float* __restrict__ out) {

    __shared__ __attribute__((aligned(16))) unsigned char sfrag[FRAG_BYTES];
    __shared__ __attribute__((aligned(16))) f16 sbuf[16 * 1152];   // 16 waves x [16][72]

    const int tid  = threadIdx.x;
    const int wid  = tid >> 6;
    const int lane = tid & 63;
    const int lrow = lane & 15;
    const int kgrp = lane >> 4;
    const int node = blockIdx.x * 16 + wid;

    // ---------- 1. issue frag staging loads (kept in regs through topk) ----------
    f16x8 stg0, stg1, stg2, stg3, stg4;
    {
        const f16x8* gsrc = (const f16x8*)frag;
        stg0 = gsrc[tid];
        stg1 = gsrc[tid + 1024];
        stg2 = gsrc[tid + 2048];
        stg3 = gsrc[tid + 3072];
        if (tid < 768) stg4 = gsrc[tid + 4096];
    }

    // ---------- 2. per-wave top-17 of this node's D row (proven r1-r6 body) ----------
    int self = 0, nb = 0;
    {
        const float* Drow = D + (size_t)node * NN;
        float v[16];
#pragma unroll
        for (int j = 0; j < 16; ++j) v[j] = Drow[j * 64 + lane];

        for (int t = 0; t < K + 1; ++t) {
            float bv = v[0]; int bj = 0;
#pragma unroll
            for (int j = 1; j < 16; ++j)
                if (v[j] < bv) { bv = v[j]; bj = j; }
            int bidx = bj * 64 + lane;
#pragma unroll
            for (int off = 32; off > 0; off >>= 1) {
                float ov = __shfl_xor(bv, off);
                int   oi = __shfl_xor(bidx, off);
                if (ov < bv || (ov == bv && oi < bidx)) { bv = ov; bidx = oi; }
            }
            if (t == 0) self = bidx;
            else if (lrow == t - 1) nb = bidx;       // lane owns edge lrow
            if ((bidx & 63) == lane) v[bidx >> 6] = INFINITY;
        }
    }

    // ---------- 3. write staged frags to LDS, sync ----------
    {
        f16x8* ldst = (f16x8*)sfrag;
        ldst[tid]        = stg0;
        ldst[tid + 1024] = stg1;
        ldst[tid + 2048] = stg2;
        ldst[tid + 3072] = stg3;
        if (tid < 768) ldst[tid + 4096] = stg4;
    }
    __syncthreads();

    const unsigned char* fb = sfrag;
    f16* buf = sbuf + wid * 1152;

    // ---------- load x1/x2, build A-frags, compute d ----------
    const float* hb = h + ((size_t)(node >> 10) << 16);

    f16x8 x1f[2], lrf[2];
    float dp = 0.f;
#pragma unroll
    for (int kt = 0; kt < 2; ++kt) {
        const float* p1 = hb + nb * 64 + kt * 32 + kgrp * 8;
        const float* p2 = hb + self * 64 + kt * 32 + kgrp * 8;
        float4 a0 = *(const float4*)(p1);
        float4 a1 = *(const float4*)(p1 + 4);
        float4 s0 = *(const float4*)(p2);
        float4 s1 = *(const float4*)(p2 + 4);
        float xs[8] = {a0.x,a0.y,a0.z,a0.w,a1.x,a1.y,a1.z,a1.w};
        float ss[8] = {s0.x,s0.y,s0.z,s0.w,s1.x,s1.y,s1.z,s1.w};
#pragma unroll
        for (int i = 0; i < 8; ++i) {
            float t = xs[i] - ss[i];
            x1f[kt][i] = (f16)xs[i];
            lrf[kt][i] = (f16)t;
            dp = fmaf(t, t, dp);
        }
    }
    dp += __shfl_xor(dp, 16);
    dp += __shfl_xor(dp, 32);
    const float dv = dp;

    // ---------- phase 1: lab = leakyReLU(lr @ W0 + b0) ----------
    f32x4 labf[4];
#pragma unroll
    for (int nt = 0; nt < 4; ++nt) {
        float bb = b0[nt * 16 + lrow];
        labf[nt] = (f32x4){bb, bb, bb, bb};
    }
#pragma unroll
    for (int kt = 0; kt < 2; ++kt)
#pragma unroll
        for (int nt = 0; nt < 4; ++nt) {
            f16x8 bf = *(const f16x8*)(fb + W0F_OFF + (kt * 4 + nt) * 1024 + lane * 16);
            labf[nt] = MFMA16(lrf[kt], bf, labf[nt]);
        }
#pragma unroll
    for (int nt = 0; nt < 4; ++nt)
#pragma unroll
        for (int j = 0; j < 4; ++j) {
            float v = labf[nt][j];
            v = v > 0.f ? v : 0.02f * v;
            labf[nt][j] = v;
            buf[(kgrp*4 + j) * 72 + nt*16 + lrow] = (f16)v;
        }

    // ---------- thl = lab@Wl + bl ; b1x = x1 @ b1^T ----------
    f32x4 thlf, b1xf;
    {
        float blv = bl[lrow];
        thlf = (f32x4){blv, blv, blv, blv};
        b1xf = (f32x4){0.f, 0.f, 0.f, 0.f};
#pragma unroll
        for (int kt = 0; kt < 2; ++kt) {
            f16x8 wl = *(const f16x8*)(fb + WLF_OFF + kt * 1024 + lane * 16);
            f16x8 bb = *(const f16x8*)(fb + B1F_OFF + kt * 1024 + lane * 16);
            f16x8 la = *(const f16x8*)&buf[lrow * 72 + kt*32 + kgrp*8];
            thlf = MFMA16(la, wl, thlf);
            b1xf = MFMA16(x1f[kt], bb, b1xf);
        }
    }

    // ---------- q-loop (fully unrolled) ----------
    f32x4 xof[4];
#pragma unroll
    for (int nt = 0; nt < 4; ++nt) xof[nt] = (f32x4){0.f, 0.f, 0.f, 0.f};

#pragma unroll
    for (int q = 0; q < 4; ++q) {
        // U_q = x1 @ W1_q
        f32x4 Uf[4];
#pragma unroll
        for (int nt = 0; nt < 4; ++nt) Uf[nt] = (f32x4){0.f, 0.f, 0.f, 0.f};
#pragma unroll
        for (int kt = 0; kt < 2; ++kt)
#pragma unroll
            for (int nt = 0; nt < 4; ++nt) {
                f16x8 bf = *(const f16x8*)(fb + W1F_OFF + (q*8 + kt*4 + nt) * 1024 + lane * 16);
                Uf[nt] = MFMA16(x1f[kt], bf, Uf[nt]);
            }

        // rolled dots: shifts {0,32,48} -> tile shifts {0,2,3}; DPP row-sum
        f32x4 dsv[3];
#pragma unroll
        for (int si = 0; si < 3; ++si) {
            const int ts = (si == 0) ? 0 : (si == 1) ? 2 : 3;
            f32x4 p = labf[0] * Uf[(0 + ts) & 3];
            p += labf[1] * Uf[(1 + ts) & 3];
            p += labf[2] * Uf[(2 + ts) & 3];
            p += labf[3] * Uf[(3 + ts) & 3];
#pragma unroll
            for (int j = 0; j < 4; ++j) p[j] = rowsum16(p[j]);
            dsv[si] = p;
        }

        // xr_p = (d_{s(p)} + b1x[4p+q]) * thl[4p+q], broadcast from col 4p+q
        f32x4 xr[4];
#pragma unroll
        for (int p = 0; p < 4; ++p) {
            const int si = (p == 1) ? 1 : (p == 2) ? 2 : 0;
            f32x4 cand = (dsv[si] + b1xf) * thlf;
            int srcl = (lane & 48) | (p * 4 + q);
#pragma unroll
            for (int j = 0; j < 4; ++j) xr[p][j] = __shfl(cand[j], srcl);
        }

        // vq = lab*(xr0+xr3) + labroll32*xr1 + labroll48*xr2 ; stage as f16 A
        {
            f32x4 x03 = xr[0] + xr[3];
#pragma unroll
            for (int nt = 0; nt < 4; ++nt) {
                f32x4 v = labf[nt] * x03
                        + labf[(nt + 2) & 3] * xr[1]
                        + labf[(nt + 1) & 3] * xr[2];
#pragma unroll
                for (int j = 0; j < 4; ++j)
                    buf[(kgrp*4 + j) * 72 + nt*16 + lrow] = (f16)v[j];
            }
        }

        // xo += vq @ W2_q
#pragma unroll
        for (int kt = 0; kt < 2; ++kt) {
            f16x8 av = *(const f16x8*)&buf[lrow * 72 + kt*32 + kgrp*8];
#pragma unroll
            for (int nt = 0; nt < 4; ++nt) {
                f16x8 bf = *(const f16x8*)(fb + W2F_OFF + (q*8 + kt*4 + nt) * 1024 + lane * 16);
                xof[nt] = MFMA16(av, bf, xof[nt]);
            }
        }

        // b2 term
#pragma unroll
        for (int p = 0; p < 4; ++p)
#pragma unroll
            for (int nt = 0; nt < 4; ++nt) {
                float bv = b2[(p*4 + q) * 64 + nt*16 + lrow];
                xof[nt] += xr[p] * bv;
            }
    }

    // ---------- epilogue: weighted sum over the 16 edges ----------
    f32x4 ew;
#pragma unroll
    for (int j = 0; j < 4; ++j) {
        float dd = __shfl(dv, kgrp * 4 + j);
        ew[j] = __expf(-dd * 0.1f);
    }
    float cs[4];
#pragma unroll
    for (int nt = 0; nt < 4; ++nt) {
        f32x4 wp = xof[nt] * ew;
        float s = wp[0] + wp[1] + wp[2] + wp[3];
        s += __shfl_xor(s, 16);
        s += __shfl_xor(s, 32);
        cs[nt] = s;
    }
    float v = (kgrp == 0) ? cs[0] : (kgrp == 1) ? cs[1] : (kgrp == 2) ? cs[2] : cs[3];
    out[(size_t)node * 64 + lane] = v;
}

extern "C" void kernel_launch(void* const* d_in, const int* in_sizes, int n_in,
                              void* d_out, int out_size, void* d_ws, size_t ws_size,
                              hipStream_t stream) {
    const float* h  = (const float*)d_in[0];
    const float* D  = (const float*)d_in[1];
    const float* W0 = (const float*)d_in[2];
    const float* b0 = (const float*)d_in[3];
    const float* W1 = (const float*)d_in[4];
    const float* b1 = (const float*)d_in[5];
    const float* W2 = (const float*)d_in[6];
    const float* b2 = (const float*)d_in[7];
    const float* Wl = (const float*)d_in[8];
    const float* bl = (const float*)d_in[9];
    float* out = (float*)d_out;

    f16* frag = (f16*)d_ws;    // 77824 bytes

    prep_kernel<<<19, 256, 0, stream>>>(W0, W1, W2, Wl, b1, frag);
    node_kernel<<<256, 1024, 0, stream>>>(h, D, b0, b2, bl, frag, out);
}

// Round 11
// 44.135 us; speedup vs baseline: 1.0109x; 1.0109x over previous
//
#include <hip/hip_runtime.h>
#include <math.h>

#define NN 1024
#define K 16

typedef _Float16 f16;
typedef f16 f16x8 __attribute__((ext_vector_type(8)));
typedef float f32x4 __attribute__((ext_vector_type(4)));

typedef __attribute__((address_space(1))) void gvoid;
typedef __attribute__((address_space(3))) void svoid;

// fragment region byte offsets (within f16 frag buffer; same layout in d_ws and LDS)
#define W0F_OFF 0          // 8 frags  (kt2 x nt4)
#define W1F_OFF 8192       // 32 frags (q4 x kt2 x nt4)
#define W2F_OFF 40960      // 32 frags (q4 x kt2 x nt4)
#define WLF_OFF 73728      // 2 frags  (kt2)
#define B1F_OFF 75776      // 2 frags  (kt2)
#define FRAG_BYTES 77824   // 76 frags x 1KB  (= 4864 x 16B)

#define MFMA16(a,b,c) __builtin_amdgcn_mfma_f32_16x16x32_f16((a),(b),(c),0,0,0)

// ---- DPP cross-lane helpers (VALU pipe, not DS) ----
template<int CTRL>
__device__ __forceinline__ float dppf(float v) {
    return __int_as_float(__builtin_amdgcn_update_dpp(0, __float_as_int(v), CTRL, 0xF, 0xF, true));
}
// sum over each aligned group of 16 lanes; result replicated in all 16
__device__ __forceinline__ float rowsum16(float v) {
    v += dppf<0xB1>(v);    // quad_perm [1,0,3,2]  (xor1)
    v += dppf<0x4E>(v);    // quad_perm [2,3,0,1]  (xor2)
    v += dppf<0x124>(v);   // row_ror:4
    v += dppf<0x128>(v);   // row_ror:8
    return v;
}

// -------------------- one-time weight fragmentation (tiny) --------------------
__global__ __launch_bounds__(256) void prep_kernel(const float* __restrict__ W0,
                                                   const float* __restrict__ W1,
                                                   const float* __restrict__ W2,
                                                   const float* __restrict__ Wl,
                                                   const float* __restrict__ b1,
                                                   f16* __restrict__ frag) {
    int c = blockIdx.x * 256 + threadIdx.x;   // 0..4863
    if (c >= 76 * 64) return;
    int fg   = c >> 6;
    int lane = c & 63;
    int lrow = lane & 15;
    int kgrp = lane >> 4;
    float src[8];
    if (fg < 8) {
        int kt = fg >> 2, nt = fg & 3;
        int n = nt * 16 + lrow;
#pragma unroll
        for (int i = 0; i < 8; ++i) src[i] = W0[(kt * 32 + kgrp * 8 + i) * 64 + n];
    } else if (fg < 40) {
        int t = fg - 8;
        int q = t >> 3, kt = (t >> 2) & 1, nt = t & 3;
        int f = nt * 16 + lrow;
#pragma unroll
        for (int i = 0; i < 8; ++i) src[i] = W1[f * 256 + q * 64 + kt * 32 + kgrp * 8 + i];
    } else if (fg < 72) {
        int t = fg - 40;
        int q = t >> 3, kt = (t >> 2) & 1, nt = t & 3;
        int o = nt * 16 + lrow;
#pragma unroll
        for (int i = 0; i < 8; ++i) src[i] = W2[(kt * 32 + kgrp * 8 + i) * 256 + q * 64 + o];
    } else if (fg < 74) {
        int kt = fg - 72;
#pragma unroll
        for (int i = 0; i < 8; ++i) src[i] = Wl[(kt * 32 + kgrp * 8 + i) * 16 + lrow];
    } else {
        int kt = fg - 74;
#pragma unroll
        for (int i = 0; i < 8; ++i) src[i] = b1[lrow * 64 + kt * 32 + kgrp * 8 + i];
    }
    f16x8 v;
#pragma unroll
    for (int i = 0; i < 8; ++i) v[i] = (f16)src[i];
    *(f16x8*)((unsigned char*)frag + fg * 1024 + lane * 16) = v;
}

// -------------------- fused main: topk + GEMM pipeline --------------------
// 256 blocks x 1024 threads (16 waves) = 1 block/CU. Wave = 1 node.
// Frag staging via async global_load_lds (issued first, drains at the barrier);
// per-wave topk runs meanwhile; then the MFMA pipeline with LDS weights.
__global__ __launch_bounds__(1024, 4) void node_kernel(
    const float* __restrict__ h, const float* __restrict__ D,
    const float* __restrict__ b0, const float* __restrict__ b2,
    const float* __restrict__ bl,
    const f16* __restrict__ frag,
    float* __restrict__ out) {

    __shared__ __attribute__((aligned(16))) unsigned char sfrag[FRAG_BYTES];
    __shared__ __attribute__((aligned(16))) f16 sbuf[16 * 1152];   // 16 waves x [16][72]

    const int tid  = threadIdx.x;
    const int wid  = tid >> 6;
    const int lane = tid & 63;
    const int lrow = lane & 15;
    const int kgrp = lane >> 4;
    const int node = blockIdx.x * 16 + wid;

    // ---------- 1. async frag staging: global -> LDS, no VGPR round-trip ----------
    {
        const unsigned char* gbase = (const unsigned char*)frag;
#pragma unroll
        for (int it = 0; it < 5; ++it) {
            int chunk = it * 1024 + wid * 64;          // 16B-unit index of wave's chunk base
            if (chunk < 4864) {                        // wave-uniform predicate
                __builtin_amdgcn_global_load_lds(
                    (gvoid*)(gbase + (size_t)(chunk + lane) * 16),   // per-lane src
                    (svoid*)(sfrag + (size_t)chunk * 16),            // wave-uniform dst (+lane*16 by HW)
                    16, 0, 0);
            }
        }
    }

    // ---------- 2. per-wave top-17 of this node's D row (proven r1-r6 body) ----------
    int self = 0, nb = 0;
    {
        const float* Drow = D + (size_t)node * NN;
        float v[16];
#pragma unroll
        for (int j = 0; j < 16; ++j) v[j] = Drow[j * 64 + lane];

        for (int t = 0; t < K + 1; ++t) {
            float bv = v[0]; int bj = 0;
#pragma unroll
            for (int j = 1; j < 16; ++j)
                if (v[j] < bv) { bv = v[j]; bj = j; }
            int bidx = bj * 64 + lane;
#pragma unroll
            for (int off = 32; off > 0; off >>= 1) {
                float ov = __shfl_xor(bv, off);
                int   oi = __shfl_xor(bidx, off);
                if (ov < bv || (ov == bv && oi < bidx)) { bv = ov; bidx = oi; }
            }
            if (t == 0) self = bidx;
            else if (lrow == t - 1) nb = bidx;       // lane owns edge lrow
            if ((bidx & 63) == lane) v[bidx >> 6] = INFINITY;
        }
    }

    // ---------- 3. barrier: drains the async LDS loads (vmcnt) + syncs waves ----------
    __syncthreads();

    const unsigned char* fb = sfrag;
    f16* buf = sbuf + wid * 1152;

    // ---------- load x1/x2, build A-frags, compute d ----------
    const float* hb = h + ((size_t)(node >> 10) << 16);

    f16x8 x1f[2], lrf[2];
    float dp = 0.f;
#pragma unroll
    for (int kt = 0; kt < 2; ++kt) {
        const float* p1 = hb + nb * 64 + kt * 32 + kgrp * 8;
        const float* p2 = hb + self * 64 + kt * 32 + kgrp * 8;
        float4 a0 = *(const float4*)(p1);
        float4 a1 = *(const float4*)(p1 + 4);
        float4 s0 = *(const float4*)(p2);
        float4 s1 = *(const float4*)(p2 + 4);
        float xs[8] = {a0.x,a0.y,a0.z,a0.w,a1.x,a1.y,a1.z,a1.w};
        float ss[8] = {s0.x,s0.y,s0.z,s0.w,s1.x,s1.y,s1.z,s1.w};
#pragma unroll
        for (int i = 0; i < 8; ++i) {
            float t = xs[i] - ss[i];
            x1f[kt][i] = (f16)xs[i];
            lrf[kt][i] = (f16)t;
            dp = fmaf(t, t, dp);
        }
    }
    dp += __shfl_xor(dp, 16);
    dp += __shfl_xor(dp, 32);
    const float dv = dp;

    // ---------- phase 1: lab = leakyReLU(lr @ W0 + b0) ----------
    f32x4 labf[4];
#pragma unroll
    for (int nt = 0; nt < 4; ++nt) {
        float bb = b0[nt * 16 + lrow];
        labf[nt] = (f32x4){bb, bb, bb, bb};
    }
#pragma unroll
    for (int kt = 0; kt < 2; ++kt)
#pragma unroll
        for (int nt = 0; nt < 4; ++nt) {
            f16x8 bf = *(const f16x8*)(fb + W0F_OFF + (kt * 4 + nt) * 1024 + lane * 16);
            labf[nt] = MFMA16(lrf[kt], bf, labf[nt]);
        }
#pragma unroll
    for (int nt = 0; nt < 4; ++nt)
#pragma unroll
        for (int j = 0; j < 4; ++j) {
            float v = labf[nt][j];
            v = v > 0.f ? v : 0.02f * v;
            labf[nt][j] = v;
            buf[(kgrp*4 + j) * 72 + nt*16 + lrow] = (f16)v;
        }

    // ---------- thl = lab@Wl + bl ; b1x = x1 @ b1^T ----------
    f32x4 thlf, b1xf;
    {
        float blv = bl[lrow];
        thlf = (f32x4){blv, blv, blv, blv};
        b1xf = (f32x4){0.f, 0.f, 0.f, 0.f};
#pragma unroll
        for (int kt = 0; kt < 2; ++kt) {
            f16x8 wl = *(const f16x8*)(fb + WLF_OFF + kt * 1024 + lane * 16);
            f16x8 bb = *(const f16x8*)(fb + B1F_OFF + kt * 1024 + lane * 16);
            f16x8 la = *(const f16x8*)&buf[lrow * 72 + kt*32 + kgrp*8];
            thlf = MFMA16(la, wl, thlf);
            b1xf = MFMA16(x1f[kt], bb, b1xf);
        }
    }

    // ---------- q-loop (fully unrolled) ----------
    f32x4 xof[4];
#pragma unroll
    for (int nt = 0; nt < 4; ++nt) xof[nt] = (f32x4){0.f, 0.f, 0.f, 0.f};

#pragma unroll
    for (int q = 0; q < 4; ++q) {
        // U_q = x1 @ W1_q
        f32x4 Uf[4];
#pragma unroll
        for (int nt = 0; nt < 4; ++nt) Uf[nt] = (f32x4){0.f, 0.f, 0.f, 0.f};
#pragma unroll
        for (int kt = 0; kt < 2; ++kt)
#pragma unroll
            for (int nt = 0; nt < 4; ++nt) {
                f16x8 bf = *(const f16x8*)(fb + W1F_OFF + (q*8 + kt*4 + nt) * 1024 + lane * 16);
                Uf[nt] = MFMA16(x1f[kt], bf, Uf[nt]);
            }

        // rolled dots: shifts {0,32,48} -> tile shifts {0,2,3}; DPP row-sum
        f32x4 dsv[3];
#pragma unroll
        for (int si = 0; si < 3; ++si) {
            const int ts = (si == 0) ? 0 : (si == 1) ? 2 : 3;
            f32x4 p = labf[0] * Uf[(0 + ts) & 3];
            p += labf[1] * Uf[(1 + ts) & 3];
            p += labf[2] * Uf[(2 + ts) & 3];
            p += labf[3] * Uf[(3 + ts) & 3];
#pragma unroll
            for (int j = 0; j < 4; ++j) p[j] = rowsum16(p[j]);
            dsv[si] = p;
        }

        // xr_p = (d_{s(p)} + b1x[4p+q]) * thl[4p+q], broadcast from col 4p+q
        f32x4 xr[4];
#pragma unroll
        for (int p = 0; p < 4; ++p) {
            const int si = (p == 1) ? 1 : (p == 2) ? 2 : 0;
            f32x4 cand = (dsv[si] + b1xf) * thlf;
            int srcl = (lane & 48) | (p * 4 + q);
#pragma unroll
            for (int j = 0; j < 4; ++j) xr[p][j] = __shfl(cand[j], srcl);
        }

        // vq = lab*(xr0+xr3) + labroll32*xr1 + labroll48*xr2 ; stage as f16 A
        {
            f32x4 x03 = xr[0] + xr[3];
#pragma unroll
            for (int nt = 0; nt < 4; ++nt) {
                f32x4 v = labf[nt] * x03
                        + labf[(nt + 2) & 3] * xr[1]
                        + labf[(nt + 1) & 3] * xr[2];
#pragma unroll
                for (int j = 0; j < 4; ++j)
                    buf[(kgrp*4 + j) * 72 + nt*16 + lrow] = (f16)v[j];
            }
        }

        // xo += vq @ W2_q
#pragma unroll
        for (int kt = 0; kt < 2; ++kt) {
            f16x8 av = *(const f16x8*)&buf[lrow * 72 + kt*32 + kgrp*8];
#pragma unroll
            for (int nt = 0; nt < 4; ++nt) {
                f16x8 bf = *(const f16x8*)(fb + W2F_OFF + (q*8 + kt*4 + nt) * 1024 + lane * 16);
                xof[nt] = MFMA16(av, bf, xof[nt]);
            }
        }

        // b2 term
#pragma unroll
        for (int p = 0; p < 4; ++p)
#pragma unroll
            for (int nt = 0; nt < 4; ++nt) {
                float bv = b2[(p*4 + q) * 64 + nt*16 + lrow];
                xof[nt] += xr[p] * bv;
            }
    }

    // ---------- epilogue: weighted sum over the 16 edges ----------
    f32x4 ew;
#pragma unroll
    for (int j = 0; j < 4; ++j) {
        float dd = __shfl(dv, kgrp * 4 + j);
        ew[j] = __expf(-dd * 0.1f);
    }
    float cs[4];
#pragma unroll
    for (int nt = 0; nt < 4; ++nt) {
        f32x4 wp = xof[nt] * ew;
        float s = wp[0] + wp[1] + wp[2] + wp[3];
        s += __shfl_xor(s, 16);
        s += __shfl_xor(s, 32);
        cs[nt] = s;
    }
    float v = (kgrp == 0) ? cs[0] : (kgrp == 1) ? cs[1] : (kgrp == 2) ? cs[2] : cs[3];
    out[(size_t)node * 64 + lane] = v;
}

extern "C" void kernel_launch(void* const* d_in, const int* in_sizes, int n_in,
                              void* d_out, int out_size, void* d_ws, size_t ws_size,
                              hipStream_t stream) {
    const float* h  = (const float*)d_in[0];
    const float* D  = (const float*)d_in[1];
    const float* W0 = (const float*)d_in[2];
    const float* b0 = (const float*)d_in[3];
    const float* W1 = (const float*)d_in[4];
    const float* b1 = (const float*)d_in[5];
    const float* W2 = (const float*)d_in[6];
    const float* b2 = (const float*)d_in[7];
    const float* Wl = (const float*)d_in[8];
    const float* bl = (const float*)d_in[9];
    float* out = (float*)d_out;

    f16* frag = (f16*)d_ws;    // 77824 bytes

    prep_kernel<<<19, 256, 0, stream>>>(W0, W1, W2, Wl, b1, frag);
    node_kernel<<<256, 1024, 0, stream>>>(h, D, b0, b2, bl, frag, out);
}

// Round 12
// 39.973 us; speedup vs baseline: 1.1162x; 1.1041x over previous
//
#include <hip/hip_runtime.h>
#include <math.h>

#define NN 1024
#define K 16

typedef _Float16 f16;
typedef f16 f16x8 __attribute__((ext_vector_type(8)));
typedef float f32x4 __attribute__((ext_vector_type(4)));

typedef __attribute__((address_space(1))) void gvoid;
typedef __attribute__((address_space(3))) void svoid;

// fragment region byte offsets (within f16 frag buffer; same layout in d_ws and LDS)
#define W0F_OFF 0          // 8 frags  (kt2 x nt4)
#define W1F_OFF 8192       // 32 frags (q4 x kt2 x nt4)
#define W2F_OFF 40960      // 32 frags (q4 x kt2 x nt4)
#define WLF_OFF 73728      // 2 frags  (kt2)
#define B1F_OFF 75776      // 2 frags  (kt2)
#define FRAG_BYTES 77824   // 76 frags x 1KB  (= 4864 x 16B)

#define MFMA16(a,b,c) __builtin_amdgcn_mfma_f32_16x16x32_f16((a),(b),(c),0,0,0)

// ---- DPP cross-lane helpers (VALU pipe, not DS) ----
template<int CTRL>
__device__ __forceinline__ float dppf(float v) {
    return __int_as_float(__builtin_amdgcn_update_dpp(0, __float_as_int(v), CTRL, 0xF, 0xF, true));
}
template<int CTRL>
__device__ __forceinline__ int dppi(int v) {
    return __builtin_amdgcn_update_dpp(0, v, CTRL, 0xF, 0xF, true);
}
// sum over each aligned group of 16 lanes; result replicated in all 16
__device__ __forceinline__ float rowsum16(float v) {
    v += dppf<0xB1>(v);    // quad_perm [1,0,3,2]  (xor1)
    v += dppf<0x4E>(v);    // quad_perm [2,3,0,1]  (xor2)
    v += dppf<0x124>(v);   // row_ror:4
    v += dppf<0x128>(v);   // row_ror:8
    return v;
}
__device__ __forceinline__ void argmin_step(float& bv, int& bidx, float ov, int oi) {
    bool t = (ov < bv) || (ov == bv && oi < bidx);
    bv = t ? ov : bv;
    bidx = t ? oi : bidx;
}

// -------------------- fused: topk (blocks 0..1023) + weight prep (1024..1042) --------------------
// topk: proven r1-r6 sequential-scan body; wave argmin uses DPP (r7-verified
// correct) for the 4 within-row steps, shfl for 16/32.
__global__ __launch_bounds__(256) void pre_kernel(const float* __restrict__ D,
                                                  const float* __restrict__ W0,
                                                  const float* __restrict__ W1,
                                                  const float* __restrict__ W2,
                                                  const float* __restrict__ Wl,
                                                  const float* __restrict__ b1,
                                                  int* __restrict__ selfIdx,
                                                  int* __restrict__ nbrIdx,
                                                  f16* __restrict__ frag) {
    if (blockIdx.x >= 1024) {
        int c = (blockIdx.x - 1024) * 256 + threadIdx.x;   // 0..4863
        if (c >= 76 * 64) return;
        int fg   = c >> 6;
        int lane = c & 63;
        int lrow = lane & 15;
        int kgrp = lane >> 4;
        float src[8];
        if (fg < 8) {
            int kt = fg >> 2, nt = fg & 3;
            int n = nt * 16 + lrow;
#pragma unroll
            for (int i = 0; i < 8; ++i) src[i] = W0[(kt * 32 + kgrp * 8 + i) * 64 + n];
        } else if (fg < 40) {
            int t = fg - 8;
            int q = t >> 3, kt = (t >> 2) & 1, nt = t & 3;
            int f = nt * 16 + lrow;
#pragma unroll
            for (int i = 0; i < 8; ++i) src[i] = W1[f * 256 + q * 64 + kt * 32 + kgrp * 8 + i];
        } else if (fg < 72) {
            int t = fg - 40;
            int q = t >> 3, kt = (t >> 2) & 1, nt = t & 3;
            int o = nt * 16 + lrow;
#pragma unroll
            for (int i = 0; i < 8; ++i) src[i] = W2[(kt * 32 + kgrp * 8 + i) * 256 + q * 64 + o];
        } else if (fg < 74) {
            int kt = fg - 72;
#pragma unroll
            for (int i = 0; i < 8; ++i) src[i] = Wl[(kt * 32 + kgrp * 8 + i) * 16 + lrow];
        } else {
            int kt = fg - 74;
#pragma unroll
            for (int i = 0; i < 8; ++i) src[i] = b1[lrow * 64 + kt * 32 + kgrp * 8 + i];
        }
        f16x8 v;
#pragma unroll
        for (int i = 0; i < 8; ++i) v[i] = (f16)src[i];
        *(f16x8*)((unsigned char*)frag + fg * 1024 + lane * 16) = v;
        return;
    }

    // ---- top-17 smallest per row ----
    int row  = blockIdx.x * 4 + (threadIdx.x >> 6);
    int lane = threadIdx.x & 63;
    const float* Drow = D + (size_t)row * NN;

    float v[16];
#pragma unroll
    for (int j = 0; j < 16; ++j) v[j] = Drow[j * 64 + lane];

    for (int t = 0; t < K + 1; ++t) {
        float bv = v[0]; int bj = 0;
#pragma unroll
        for (int j = 1; j < 16; ++j)
            if (v[j] < bv) { bv = v[j]; bj = j; }
        int bidx = bj * 64 + lane;
        // wave argmin: 4 DPP steps (within 16 lanes) + 2 shfl (16, 32)
        argmin_step(bv, bidx, dppf<0xB1>(bv),  dppi<0xB1>(bidx));
        argmin_step(bv, bidx, dppf<0x4E>(bv),  dppi<0x4E>(bidx));
        argmin_step(bv, bidx, dppf<0x124>(bv), dppi<0x124>(bidx));
        argmin_step(bv, bidx, dppf<0x128>(bv), dppi<0x128>(bidx));
        argmin_step(bv, bidx, __shfl_xor(bv, 16), __shfl_xor(bidx, 16));
        argmin_step(bv, bidx, __shfl_xor(bv, 32), __shfl_xor(bidx, 32));

        if (lane == 0) {
            if (t == 0) selfIdx[row] = bidx;
            else        nbrIdx[row * K + (t - 1)] = bidx;
        }
        if ((bidx & 63) == lane) v[bidx >> 6] = INFINITY;
    }
}

// -------------------- main: 1 block per CU (16 waves), wave = 1 node --------------------
// Async frag staging (global_load_lds) issued first; idx/x1/x2/d phase runs
// while it drains; barrier; then the MFMA pipeline reads weights from LDS.
// launch_bounds(1024,4): VGPR cap 128 — prevents the 64-VGPR spill allocation.
__global__ __launch_bounds__(1024, 4) void node_kernel(
    const float* __restrict__ h,
    const float* __restrict__ b0, const float* __restrict__ b2,
    const float* __restrict__ bl,
    const f16* __restrict__ frag,
    const int* __restrict__ selfIdx, const int* __restrict__ nbrIdx,
    float* __restrict__ out) {

    __shared__ __attribute__((aligned(16))) unsigned char sfrag[FRAG_BYTES];
    __shared__ __attribute__((aligned(16))) f16 sbuf[16 * 1152];   // 16 waves x [16][72]

    const int tid  = threadIdx.x;
    const int wid  = tid >> 6;
    const int lane = tid & 63;
    const int lrow = lane & 15;
    const int kgrp = lane >> 4;
    const int node = blockIdx.x * 16 + wid;

    // ---------- 1. async frag staging: global -> LDS, no VGPR round-trip ----------
    {
        const unsigned char* gbase = (const unsigned char*)frag;
#pragma unroll
        for (int it = 0; it < 5; ++it) {
            int chunk = it * 1024 + wid * 64;          // 16B-unit index (wave-uniform)
            if (chunk < 4864) {
                __builtin_amdgcn_global_load_lds(
                    (gvoid*)(gbase + (size_t)(chunk + lane) * 16),   // per-lane src
                    (svoid*)(sfrag + (size_t)chunk * 16),            // wave-uniform dst
                    16, 0, 0);
            }
        }
    }

    // ---------- 2. idx + x1/x2 load, A-frags, d  (no sfrag use -> overlaps staging) ----------
    const int self = selfIdx[node];
    const int nb   = nbrIdx[node * 16 + lrow];
    const float* hb = h + ((size_t)(node >> 10) << 16);

    f16x8 x1f[2], lrf[2];
    float dp = 0.f;
#pragma unroll
    for (int kt = 0; kt < 2; ++kt) {
        const float* p1 = hb + nb * 64 + kt * 32 + kgrp * 8;
        const float* p2 = hb + self * 64 + kt * 32 + kgrp * 8;
        float4 a0 = *(const float4*)(p1);
        float4 a1 = *(const float4*)(p1 + 4);
        float4 s0 = *(const float4*)(p2);
        float4 s1 = *(const float4*)(p2 + 4);
        float xs[8] = {a0.x,a0.y,a0.z,a0.w,a1.x,a1.y,a1.z,a1.w};
        float ss[8] = {s0.x,s0.y,s0.z,s0.w,s1.x,s1.y,s1.z,s1.w};
#pragma unroll
        for (int i = 0; i < 8; ++i) {
            float t = xs[i] - ss[i];
            x1f[kt][i] = (f16)xs[i];
            lrf[kt][i] = (f16)t;
            dp = fmaf(t, t, dp);
        }
    }
    dp += __shfl_xor(dp, 16);
    dp += __shfl_xor(dp, 32);
    const float dv = dp;

    // ---------- 3. barrier: drains async LDS loads + syncs ----------
    __syncthreads();

    const unsigned char* fb = sfrag;
    f16* buf = sbuf + wid * 1152;

    // ---------- phase 1: lab = leakyReLU(lr @ W0 + b0) ----------
    f32x4 labf[4];
#pragma unroll
    for (int nt = 0; nt < 4; ++nt) {
        float bb = b0[nt * 16 + lrow];
        labf[nt] = (f32x4){bb, bb, bb, bb};
    }
#pragma unroll
    for (int kt = 0; kt < 2; ++kt)
#pragma unroll
        for (int nt = 0; nt < 4; ++nt) {
            f16x8 bf = *(const f16x8*)(fb + W0F_OFF + (kt * 4 + nt) * 1024 + lane * 16);
            labf[nt] = MFMA16(lrf[kt], bf, labf[nt]);
        }
#pragma unroll
    for (int nt = 0; nt < 4; ++nt)
#pragma unroll
        for (int j = 0; j < 4; ++j) {
            float v = labf[nt][j];
            v = v > 0.f ? v : 0.02f * v;
            labf[nt][j] = v;
            buf[(kgrp*4 + j) * 72 + nt*16 + lrow] = (f16)v;
        }

    // ---------- thl = lab@Wl + bl ; b1x = x1 @ b1^T ----------
    f32x4 thlf, b1xf;
    {
        float blv = bl[lrow];
        thlf = (f32x4){blv, blv, blv, blv};
        b1xf = (f32x4){0.f, 0.f, 0.f, 0.f};
#pragma unroll
        for (int kt = 0; kt < 2; ++kt) {
            f16x8 wl = *(const f16x8*)(fb + WLF_OFF + kt * 1024 + lane * 16);
            f16x8 bb = *(const f16x8*)(fb + B1F_OFF + kt * 1024 + lane * 16);
            f16x8 la = *(const f16x8*)&buf[lrow * 72 + kt*32 + kgrp*8];
            thlf = MFMA16(la, wl, thlf);
            b1xf = MFMA16(x1f[kt], bb, b1xf);
        }
    }

    // ---------- q-loop (fully unrolled) ----------
    f32x4 xof[4];
#pragma unroll
    for (int nt = 0; nt < 4; ++nt) xof[nt] = (f32x4){0.f, 0.f, 0.f, 0.f};

#pragma unroll
    for (int q = 0; q < 4; ++q) {
        // U_q = x1 @ W1_q
        f32x4 Uf[4];
#pragma unroll
        for (int nt = 0; nt < 4; ++nt) Uf[nt] = (f32x4){0.f, 0.f, 0.f, 0.f};
#pragma unroll
        for (int kt = 0; kt < 2; ++kt)
#pragma unroll
            for (int nt = 0; nt < 4; ++nt) {
                f16x8 bf = *(const f16x8*)(fb + W1F_OFF + (q*8 + kt*4 + nt) * 1024 + lane * 16);
                Uf[nt] = MFMA16(x1f[kt], bf, Uf[nt]);
            }

        // rolled dots: shifts {0,32,48} -> tile shifts {0,2,3}; DPP row-sum
        f32x4 dsv[3];
#pragma unroll
        for (int si = 0; si < 3; ++si) {
            const int ts = (si == 0) ? 0 : (si == 1) ? 2 : 3;
            f32x4 p = labf[0] * Uf[(0 + ts) & 3];
            p += labf[1] * Uf[(1 + ts) & 3];
            p += labf[2] * Uf[(2 + ts) & 3];
            p += labf[3] * Uf[(3 + ts) & 3];
#pragma unroll
            for (int j = 0; j < 4; ++j) p[j] = rowsum16(p[j]);
            dsv[si] = p;
        }

        // xr_p = (d_{s(p)} + b1x[4p+q]) * thl[4p+q], broadcast from col 4p+q
        f32x4 xr[4];
#pragma unroll
        for (int p = 0; p < 4; ++p) {
            const int si = (p == 1) ? 1 : (p == 2) ? 2 : 0;
            f32x4 cand = (dsv[si] + b1xf) * thlf;
            int srcl = (lane & 48) | (p * 4 + q);
#pragma unroll
            for (int j = 0; j < 4; ++j) xr[p][j] = __shfl(cand[j], srcl);
        }

        // vq = lab*(xr0+xr3) + labroll32*xr1 + labroll48*xr2 ; stage as f16 A
        {
            f32x4 x03 = xr[0] + xr[3];
#pragma unroll
            for (int nt = 0; nt < 4; ++nt) {
                f32x4 v = labf[nt] * x03
                        + labf[(nt + 2) & 3] * xr[1]
                        + labf[(nt + 1) & 3] * xr[2];
#pragma unroll
                for (int j = 0; j < 4; ++j)
                    buf[(kgrp*4 + j) * 72 + nt*16 + lrow] = (f16)v[j];
            }
        }

        // xo += vq @ W2_q
#pragma unroll
        for (int kt = 0; kt < 2; ++kt) {
            f16x8 av = *(const f16x8*)&buf[lrow * 72 + kt*32 + kgrp*8];
#pragma unroll
            for (int nt = 0; nt < 4; ++nt) {
                f16x8 bf = *(const f16x8*)(fb + W2F_OFF + (q*8 + kt*4 + nt) * 1024 + lane * 16);
                xof[nt] = MFMA16(av, bf, xof[nt]);
            }
        }

        // b2 term
#pragma unroll
        for (int p = 0; p < 4; ++p)
#pragma unroll
            for (int nt = 0; nt < 4; ++nt) {
                float bv = b2[(p*4 + q) * 64 + nt*16 + lrow];
                xof[nt] += xr[p] * bv;
            }
    }

    // ---------- epilogue: weighted sum over the 16 edges ----------
    f32x4 ew;
#pragma unroll
    for (int j = 0; j < 4; ++j) {
        float dd = __shfl(dv, kgrp * 4 + j);
        ew[j] = __expf(-dd * 0.1f);
    }
    float cs[4];
#pragma unroll
    for (int nt = 0; nt < 4; ++nt) {
        f32x4 wp = xof[nt] * ew;
        float s = wp[0] + wp[1] + wp[2] + wp[3];
        s += __shfl_xor(s, 16);
        s += __shfl_xor(s, 32);
        cs[nt] = s;
    }
    float v = (kgrp == 0) ? cs[0] : (kgrp == 1) ? cs[1] : (kgrp == 2) ? cs[2] : cs[3];
    out[(size_t)node * 64 + lane] = v;
}

extern "C" void kernel_launch(void* const* d_in, const int* in_sizes, int n_in,
                              void* d_out, int out_size, void* d_ws, size_t ws_size,
                              hipStream_t stream) {
    const float* h  = (const float*)d_in[0];
    const float* D  = (const float*)d_in[1];
    const float* W0 = (const float*)d_in[2];
    const float* b0 = (const float*)d_in[3];
    const float* W1 = (const float*)d_in[4];
    const float* b1 = (const float*)d_in[5];
    const float* W2 = (const float*)d_in[6];
    const float* b2 = (const float*)d_in[7];
    const float* Wl = (const float*)d_in[8];
    const float* bl = (const float*)d_in[9];
    float* out = (float*)d_out;

    int* selfIdx = (int*)d_ws;            // 4096 ints
    int* nbrIdx  = selfIdx + 4096;        // 65536 ints
    f16* frag    = (f16*)(nbrIdx + 65536);// 77824 bytes

    pre_kernel<<<1043, 256, 0, stream>>>(D, W0, W1, W2, Wl, b1,
                                         selfIdx, nbrIdx, frag);
    node_kernel<<<256, 1024, 0, stream>>>(h, b0, b2, bl, frag,
                                          selfIdx, nbrIdx, out);
}